// Round 6
// baseline (2360.977 us; speedup 1.0000x reference)
//
#include <hip/hip_runtime.h>
#include <stdint.h>

#define T_DIM 2048
#define B_DIM 1024
#define A_DIM 4
#define D_DIM 128
#define TC 32                   // scan steps per chunk (input prefetch granularity)
#define HTC 16                  // steps per half-chunk (scan->GEMM granularity)
#define NCHUNK (T_DIM / TC)
#define LDH 136                 // Hb row stride in bf16 elems (68 dwords == 4 mod 32 -> conflict-free b128)
#define LDC 136                 // Ct staging row stride
#define HB_BYTES (64 * LDH * 2)         // 17408 (64 rows: 4 waves x 16 steps)
#define QT_S 33                 // Qt col stride in dwords (32 m2 slots + 1 pad)
// LDS high-water mark is the init-time Ct staging (144*LDC*2 = 39168);
// main-loop overlay Hb(17408)+Qt(16896)=34304 fits inside it.
// 39168 B -> 4 blocks/CU (4*39168=156672 <= 160KiB), VGPR<=128 via launch_bounds.
#define SMEM_BYTES (144 * LDC * 2)      // 39168

typedef __attribute__((ext_vector_type(8))) short bf16x8;
typedef __attribute__((ext_vector_type(4))) float f32x4;

__device__ __forceinline__ float clampf(float x, float lo, float hi) {
    return fminf(fmaxf(x, lo), hi);
}
__device__ __forceinline__ uint16_t bf16rnd(float f) {
    uint32_t u = __builtin_bit_cast(uint32_t, f) + 0x8000u;   // round-nearest (ties away)
    return (uint16_t)(u >> 16);
}
// pack2(x,y) -> (bf16(y)<<16)|bf16(x) in 3 VALU ops
__device__ __forceinline__ uint32_t pack2(float x, float y) {
    uint32_t ux = __builtin_bit_cast(uint32_t, x) + 0x8000u;
    uint32_t uy = __builtin_bit_cast(uint32_t, y) + 0x8000u;
    return __builtin_amdgcn_perm(uy, ux, 0x07060302);
}
__device__ __forceinline__ float bfLO(uint32_t u) {
    return __builtin_bit_cast(float, u << 16);
}
__device__ __forceinline__ float bfHI(uint32_t u) {
    return __builtin_bit_cast(float, u & 0xFFFF0000u);
}
template <int CTRL>
__device__ __forceinline__ float dppadd(float x) {
    int xi = __builtin_bit_cast(int, x);
    int yi = __builtin_amdgcn_mov_dpp(xi, CTRL, 0xF, 0xF, false);
    return x + __builtin_bit_cast(float, yi);
}
// sum across the 16 lanes of each DPP row (our ml-groups) via row_ror 1,2,4,8
__device__ __forceinline__ float rowsum16(float x) {
    x = dppadd<0x121>(x);
    x = dppadd<0x122>(x);
    x = dppadd<0x124>(x);
    x = dppadd<0x128>(x);
    return x;
}

// One block per b; 4 waves; wave wv owns action a=wv. No main-loop barriers:
// each wave only touches its own 16 rows of Hb/Qt per half-chunk. Ct
// (B-fragments) lives in registers (144 VGPRs), loaded once from an LDS
// staging area that is then overlaid by Hb/Qt.
//
// Half-chunk restructure (vs the 577us 2-block/CU version): scan 16 steps ->
// GEMM one 16-row m-tile, twice per chunk. Halves Hb/Qt so the LDS
// high-water mark is the init staging (39168B) -> 4 blocks/CU (double
// occupancy; fills the 34% idle VALU pipe observed at 2 blocks/CU).
__global__ __launch_bounds__(256, 4)
void gql_fused(const float* __restrict__ inp,
               const float* __restrict__ phi_raw,
               const float* __restrict__ chi_raw,
               const float* __restrict__ beta_raw,
               const float* __restrict__ kappa_raw,
               const float* __restrict__ C_raw,
               float* __restrict__ out)
{
    __shared__ __attribute__((aligned(16))) char smem[SMEM_BYTES];

    const int b    = blockIdx.x;
    const int tid  = threadIdx.x;
    const int lane = tid & 63;
    const int wv   = tid >> 6;
    const int ml   = lane & 15;
    const int qd   = lane >> 4;

    const int pid = (int)inp[(size_t)b * 9 + 8];

    // ---- scan params: thread owns (a=wv, d0=2*lane, d0+1)
    const int d0 = lane * 2;
    float2 pr = *(const float2*)(phi_raw + (size_t)pid * D_DIM + d0);
    float2 cr = *(const float2*)(chi_raw + (size_t)pid * D_DIM + d0);
    float phi0 = clampf(1.f / (1.f + __expf(-pr.x)), 0.01f, 0.99f);
    float phi1 = clampf(1.f / (1.f + __expf(-pr.y)), 0.01f, 0.99f);
    float chi0 = clampf(1.f / (1.f + __expf(-cr.x)), 0.01f, 0.99f);
    float chi1 = clampf(1.f / (1.f + __expf(-cr.y)), 0.01f, 0.99f);
    float omphi0 = 1.f - phi0, omphi1 = 1.f - phi1;
    float omchi0 = 1.f - chi0, omchi1 = 1.f - chi1;

    // ---- betas in registers (nt<8 real, nt=8 kappa-tile -> 0)
    float breg[9];
    #pragma unroll
    for (int nt = 0; nt < 8; ++nt) {
        float x = beta_raw[(size_t)pid * D_DIM + nt * 16 + ml];
        breg[nt] = clampf(log1pf(__expf(x)), 0.1f, 10.0f);
    }
    breg[8] = 0.f;

    // ---- stage Ct[n][k] = bf16(clip(C[k][n])) into LDS (temporary)
    {
        uint16_t* Ct = (uint16_t*)smem;
        const float* Cp = C_raw + (size_t)pid * (D_DIM * D_DIM);
        #pragma unroll 8
        for (int i = 0; i < 64; ++i) {
            int idx = i * 256 + tid;
            int d = idx >> 7, e = idx & 127;
            Ct[e * LDC + d] = bf16rnd(clampf(Cp[idx], -10.f, 10.f));
        }
        for (int i = tid; i < 16 * LDC; i += 256) {
            int n = i / LDC;
            int k = i - n * LDC;
            float v = (n == 0 && k < D_DIM)
                        ? clampf(kappa_raw[(size_t)pid * D_DIM + k], -10.f, 10.f) : 0.f;
            Ct[(128 + n) * LDC + k] = bf16rnd(v);
        }
    }
    __syncthreads();

    // ---- B-fragments to registers (chunk-invariant): bfr[nt][kt]
    bf16x8 bfr[9][4];
    {
        const uint16_t* Ct = (const uint16_t*)smem;
        #pragma unroll
        for (int nt = 0; nt < 9; ++nt)
            #pragma unroll
            for (int kt = 0; kt < 4; ++kt)
                bfr[nt][kt] = *(const bf16x8*)&Ct[(nt * 16 + ml) * LDC + kt * 32 + qd * 8];
    }
    __syncthreads();   // staging area now dead; reuse as Hb/Qt

    uint32_t* H32 = (uint32_t*)smem;                    // Hb[m][k] bf16-pairs, dword idx m*68+dpair (64 rows)
    uint32_t* Qt  = (uint32_t*)(smem + HB_BYTES);       // Qt col-major: dword(col,m2)=col*33+(m2^SW(col)), m2<32
    const uint16_t* Hb16 = (const uint16_t*)smem;
    const int SWt = ((lane >> 4) & 3) << 3;             // SW(col=2*lane) == SW(2*lane+1)

    // ---- per-chunk wave-uniform inputs via readlane: lane l<32 holds step l
    float actv, rav;
    {
        size_t t = (size_t)(lane & 31);
        const float* p = inp + (t * B_DIM + b) * 9;
        float a = p[wv], r = p[4 + wv];
        actv = a; rav = a * r;
    }

    float q0 = 0.5f, q1 = 0.5f, h0 = 0.f, h1 = 0.f;

    for (int chunk = 0; chunk < NCHUNK; ++chunk) {
        const int ai = __builtin_bit_cast(int, actv);
        const int ri = __builtin_bit_cast(int, rav);

        #pragma unroll
        for (int hf = 0; hf < 2; ++hf) {
            // ---- scan: 16 steps, register-only except paired LDS stores
            uint32_t hw_prev = 0, qwA0 = 0, qwA1 = 0;
            float q0p = 0.f, q1p = 0.f;
            #pragma unroll
            for (int tlh = 0; tlh < HTC; ++tlh) {
                const int tl = hf * HTC + tlh;
                float sa = __builtin_bit_cast(float, __builtin_amdgcn_readlane(ai, tl));
                float sr = __builtin_bit_cast(float, __builtin_amdgcn_readlane(ri, tl));
                q0 = fmaf(omphi0, q0, phi0 * sr);
                q1 = fmaf(omphi1, q1, phi1 * sr);
                h0 = fmaf(omchi0, h0, chi0 * sa);
                h1 = fmaf(omchi1, h1, chi1 * sa);
                uint32_t hw = pack2(h0, h1);
                if (tlh & 1) {
                    int m = wv * HTC + tlh - 1;
                    H32[m * 68 + lane] = hw_prev;       // rows m, m+1: ds_write2-mergeable
                    H32[(m + 1) * 68 + lane] = hw;
                } else {
                    hw_prev = hw;
                }
                if ((tlh & 1) == 0) {
                    q0p = q0; q1p = q1;
                } else if ((tlh & 3) == 1) {
                    qwA0 = pack2(q0p, q0);              // col d0, rows tlh-1,tlh
                    qwA1 = pack2(q1p, q1);              // col d0+1
                } else {                                // tlh&3 == 3
                    uint32_t qwB0 = pack2(q0p, q0);
                    uint32_t qwB1 = pack2(q1p, q1);
                    int m2  = wv * 8 + ((tlh - 3) >> 1);    // even, 0..30
                    int adw = d0 * QT_S + (m2 ^ SWt);
                    Qt[adw]     = qwA0;  Qt[adw + 1]        = qwB0;
                    Qt[adw + QT_S] = qwA1; Qt[adw + QT_S + 1] = qwB1;
                }
            }

            // prefetch next chunk's inputs after half 0 (latency hidden
            // behind half-0 GEMM+epilogue and all of half 1)
            if (hf == 0 && chunk + 1 < NCHUNK) {
                size_t t = (size_t)(chunk + 1) * TC + (lane & 31);
                const float* p = inp + (t * B_DIM + b) * 9;
                float a = p[wv], r = p[4 + wv];
                actv = a; rav = a * r;
            }

            // ---- GEMM + epilogue: this wave's 16-row m-tile (mt == wv)
            f32x4 acc[9];
            #pragma unroll
            for (int nt = 0; nt < 9; ++nt) acc[nt] = (f32x4){0.f, 0.f, 0.f, 0.f};

            #pragma unroll
            for (int kt = 0; kt < 4; ++kt) {
                bf16x8 afr = *(const bf16x8*)&Hb16[(size_t)(wv * HTC + ml) * LDH + kt * 32 + qd * 8];
                #pragma unroll
                for (int nt = 0; nt < 9; ++nt)
                    acc[nt] = __builtin_amdgcn_mfma_f32_16x16x32_bf16(afr, bfr[nt][kt], acc[nt], 0, 0, 0);
            }

            // kappa tile: col 128 lives at nt=8, ml==0; Q there == 1, beta == 0
            bool km = (ml == 0);
            float p0 = km ? acc[8][0] : 0.f;
            float p1 = km ? acc[8][1] : 0.f;
            float p2 = km ? acc[8][2] : 0.f;
            float p3 = km ? acc[8][3] : 0.f;

            const int m2e = wv * 8 + qd * 2;            // m2 of rows row0,row0+1
            #pragma unroll
            for (int nt = 0; nt < 8; ++nt) {
                const int SWc = ((nt >> 1) & 3) << 3;   // SW(col=16nt+ml), ml<16
                int adw = (nt * 16 + ml) * QT_S + (m2e ^ SWc);
                uint32_t w0 = Qt[adw];
                uint32_t w1 = Qt[adw + 1];
                float g0 = acc[nt][0] + breg[nt];
                float g1 = acc[nt][1] + breg[nt];
                float g2 = acc[nt][2] + breg[nt];
                float g3 = acc[nt][3] + breg[nt];
                p0 = fmaf(g0, bfLO(w0), p0);
                p1 = fmaf(g1, bfHI(w0), p1);
                p2 = fmaf(g2, bfLO(w1), p2);
                p3 = fmaf(g3, bfHI(w1), p3);
            }

            p0 = rowsum16(p0);
            p1 = rowsum16(p1);
            p2 = rowsum16(p2);
            p3 = rowsum16(p3);

            if (ml == 0) {
                int r0 = qd * 4;
                #pragma unroll
                for (int r = 0; r < 4; ++r) {
                    size_t t = (size_t)chunk * TC + hf * HTC + r0 + r;
                    float pv = (r == 0) ? p0 : (r == 1) ? p1 : (r == 2) ? p2 : p3;
                    out[(t * B_DIM + b) * A_DIM + wv] = pv;
                }
            }
            // no barrier: next scan overwrites only this wave's own rows
            // after its own reads (same-wave LDS ordering)
        }
    }

    // ---- final q, h (fp32 state, exact recurrence)
    size_t qbase = (size_t)T_DIM * B_DIM * A_DIM;
    size_t off = (size_t)b * (A_DIM * D_DIM) + (size_t)wv * D_DIM + d0;
    *(float2*)&out[qbase + off] = make_float2(q0, q1);
    *(float2*)&out[qbase + (size_t)B_DIM * A_DIM * D_DIM + off] = make_float2(h0, h1);
}

extern "C" void kernel_launch(void* const* d_in, const int* in_sizes, int n_in,
                              void* d_out, int out_size, void* d_ws, size_t ws_size,
                              hipStream_t stream) {
    const float* inp    = (const float*)d_in[0];
    const float* phi_r  = (const float*)d_in[1];
    const float* chi_r  = (const float*)d_in[2];
    const float* beta_r = (const float*)d_in[3];
    const float* kap_r  = (const float*)d_in[4];
    const float* C_r    = (const float*)d_in[5];
    float* outp = (float*)d_out;
    gql_fused<<<dim3(B_DIM), dim3(256), 0, stream>>>(inp, phi_r, chi_r, beta_r, kap_r, C_r, outp);
}

// Round 7
// 601.570 us; speedup vs baseline: 3.9247x; 3.9247x over previous
//
#include <hip/hip_runtime.h>
#include <stdint.h>

#define T_DIM 2048
#define B_DIM 1024
#define A_DIM 4
#define D_DIM 128
#define TC 32
#define NCHUNK (T_DIM / TC)
#define LDH 136                 // Hb row stride in bf16 elems (68 dwords == 4 mod 32 -> conflict-free b128)
#define LDC 136                 // Ct staging row stride
#define HB_BYTES (128 * LDH * 2)        // 34816
// Qt pair-interleaved: dword(col,slot) = (col>>1)*130 + 2*slot + (col&1)
//   (64 colpairs x 130 dwords = 8320 dwords = 33280 B)
// Writer banks: (65*l + s0) % 16 bank-pairs -> exactly 4 lanes/pair = NO conflict
// (old col-major stride-65 layout was a 4-way write conflict: even banks only).
#define SMEM_BYTES (HB_BYTES + 64 * 130 * 4)   // 34816 + 33280 = 68096 (<80KB -> 2 blocks/CU)

typedef __attribute__((ext_vector_type(8))) short bf16x8;
typedef __attribute__((ext_vector_type(4))) float f32x4;

__device__ __forceinline__ float clampf(float x, float lo, float hi) {
    return fminf(fmaxf(x, lo), hi);
}
__device__ __forceinline__ uint16_t bf16rnd(float f) {
    uint32_t u = __builtin_bit_cast(uint32_t, f) + 0x8000u;   // round-nearest (ties away)
    return (uint16_t)(u >> 16);
}
// pack2(x,y) -> (bf16(y)<<16)|bf16(x) in 3 VALU ops
__device__ __forceinline__ uint32_t pack2(float x, float y) {
    uint32_t ux = __builtin_bit_cast(uint32_t, x) + 0x8000u;
    uint32_t uy = __builtin_bit_cast(uint32_t, y) + 0x8000u;
    return __builtin_amdgcn_perm(uy, ux, 0x07060302);
}
__device__ __forceinline__ float bfLO(uint32_t u) {
    return __builtin_bit_cast(float, u << 16);
}
__device__ __forceinline__ float bfHI(uint32_t u) {
    return __builtin_bit_cast(float, u & 0xFFFF0000u);
}
template <int CTRL>
__device__ __forceinline__ float dppadd(float x) {
    int xi = __builtin_bit_cast(int, x);
    int yi = __builtin_amdgcn_mov_dpp(xi, CTRL, 0xF, 0xF, false);
    return x + __builtin_bit_cast(float, yi);
}
// sum across the 16 lanes of each DPP row (our ml-groups) via row_ror 1,2,4,8
__device__ __forceinline__ float rowsum16(float x) {
    x = dppadd<0x121>(x);
    x = dppadd<0x122>(x);
    x = dppadd<0x124>(x);
    x = dppadd<0x128>(x);
    return x;
}

// One block per b; 4 waves; wave wv owns action a=wv. No main-loop barriers:
// each wave only touches its own 32 rows of Hb/Qt. Ct (B-fragments) lives in
// registers (144 VGPRs), loaded once from an LDS staging area that is then
// overlaid by Hb/Qt. 66.5 KB LDS + <=256 VGPR -> 2 blocks/CU.
// (R6 lesson: bfr's 144 regs forbid >2 waves/SIMD; launch_bounds(.,4) spills
//  bfr to scratch -> 8.2GB FETCH. Keep 2 blocks/CU.)
__global__ __launch_bounds__(256, 2)
void gql_fused(const float* __restrict__ inp,
               const float* __restrict__ phi_raw,
               const float* __restrict__ chi_raw,
               const float* __restrict__ beta_raw,
               const float* __restrict__ kappa_raw,
               const float* __restrict__ C_raw,
               float* __restrict__ out)
{
    __shared__ __attribute__((aligned(16))) char smem[SMEM_BYTES];

    const int b    = blockIdx.x;
    const int tid  = threadIdx.x;
    const int lane = tid & 63;
    const int wv   = tid >> 6;
    const int ml   = lane & 15;
    const int qd   = lane >> 4;

    const int pid = (int)inp[(size_t)b * 9 + 8];

    // ---- scan params: thread owns (a=wv, d0=2*lane, d0+1)
    const int d0 = lane * 2;
    float2 pr = *(const float2*)(phi_raw + (size_t)pid * D_DIM + d0);
    float2 cr = *(const float2*)(chi_raw + (size_t)pid * D_DIM + d0);
    float phi0 = clampf(1.f / (1.f + __expf(-pr.x)), 0.01f, 0.99f);
    float phi1 = clampf(1.f / (1.f + __expf(-pr.y)), 0.01f, 0.99f);
    float chi0 = clampf(1.f / (1.f + __expf(-cr.x)), 0.01f, 0.99f);
    float chi1 = clampf(1.f / (1.f + __expf(-cr.y)), 0.01f, 0.99f);
    float omphi0 = 1.f - phi0, omphi1 = 1.f - phi1;
    float omchi0 = 1.f - chi0, omchi1 = 1.f - chi1;

    // ---- betas in registers (nt<8 real, nt=8 kappa-tile -> 0)
    float breg[9];
    #pragma unroll
    for (int nt = 0; nt < 8; ++nt) {
        float x = beta_raw[(size_t)pid * D_DIM + nt * 16 + ml];
        breg[nt] = clampf(log1pf(__expf(x)), 0.1f, 10.0f);
    }
    breg[8] = 0.f;

    // ---- stage Ct[n][k] = bf16(clip(C[k][n])) into LDS (temporary)
    {
        uint16_t* Ct = (uint16_t*)smem;
        const float* Cp = C_raw + (size_t)pid * (D_DIM * D_DIM);
        #pragma unroll 8
        for (int i = 0; i < 64; ++i) {
            int idx = i * 256 + tid;
            int d = idx >> 7, e = idx & 127;
            Ct[e * LDC + d] = bf16rnd(clampf(Cp[idx], -10.f, 10.f));
        }
        for (int i = tid; i < 16 * LDC; i += 256) {
            int n = i / LDC;
            int k = i - n * LDC;
            float v = (n == 0 && k < D_DIM)
                        ? clampf(kappa_raw[(size_t)pid * D_DIM + k], -10.f, 10.f) : 0.f;
            Ct[(128 + n) * LDC + k] = bf16rnd(v);
        }
    }
    __syncthreads();

    // ---- B-fragments to registers (chunk-invariant): bfr[nt][kt]
    bf16x8 bfr[9][4];
    {
        const uint16_t* Ct = (const uint16_t*)smem;
        #pragma unroll
        for (int nt = 0; nt < 9; ++nt)
            #pragma unroll
            for (int kt = 0; kt < 4; ++kt)
                bfr[nt][kt] = *(const bf16x8*)&Ct[(nt * 16 + ml) * LDC + kt * 32 + qd * 8];
    }
    __syncthreads();   // staging area now dead; reuse as Hb/Qt

    uint32_t* H32 = (uint32_t*)smem;                    // Hb[m][k] bf16-pairs, dword idx m*68+dpair
    uint32_t* Qt  = (uint32_t*)(smem + HB_BYTES);       // Qt pair-interleaved (see top)
    const uint16_t* Hb16 = (const uint16_t*)smem;

    // ---- per-chunk wave-uniform inputs via readlane: lane l<32 holds step l
    float actv, rav;
    {
        size_t t = (size_t)(lane & 31);
        const float* p = inp + (t * B_DIM + b) * 9;
        float a = p[wv], r = p[4 + wv];
        actv = a; rav = a * r;
    }

    const int qtw = lane * 130 + wv * 32;   // writer base (dwords): + (tl-3) per group

    float q0 = 0.5f, q1 = 0.5f, h0 = 0.f, h1 = 0.f;

    for (int chunk = 0; chunk < NCHUNK; ++chunk) {
        const int ai = __builtin_bit_cast(int, actv);
        const int ri = __builtin_bit_cast(int, rav);

        // ---- scan: 32 steps, register-only except paired LDS stores
        uint32_t hw_prev = 0, qwA0 = 0, qwA1 = 0;
        float q0p = 0.f, q1p = 0.f;
        #pragma unroll
        for (int tl = 0; tl < TC; ++tl) {
            float sa = __builtin_bit_cast(float, __builtin_amdgcn_readlane(ai, tl));
            float sr = __builtin_bit_cast(float, __builtin_amdgcn_readlane(ri, tl));
            q0 = fmaf(omphi0, q0, phi0 * sr);
            q1 = fmaf(omphi1, q1, phi1 * sr);
            h0 = fmaf(omchi0, h0, chi0 * sa);
            h1 = fmaf(omchi1, h1, chi1 * sa);
            uint32_t hw = pack2(h0, h1);
            if (tl & 1) {
                int m = wv * TC + tl - 1;
                H32[m * 68 + lane] = hw_prev;           // rows m, m+1: ds_write2-mergeable
                H32[(m + 1) * 68 + lane] = hw;
            } else {
                hw_prev = hw;
            }
            if ((tl & 1) == 0) {
                q0p = q0; q1p = q1;
            } else if ((tl & 3) == 1) {
                qwA0 = pack2(q0p, q0);                  // col d0, rows tl-1,tl
                qwA1 = pack2(q1p, q1);                  // col d0+1
            } else {                                    // tl&3 == 3
                uint32_t qwB0 = pack2(q0p, q0);
                uint32_t qwB1 = pack2(q1p, q1);
                // slots s0=wv*16+(tl-3)/2 (rows pair A), s0+1 (pair B);
                // dwords qtw+(tl-3) .. +3 = {A0,A1,B0,B1} -> 2x 8B stores
                uint32_t* qp = &Qt[qtw + (tl - 3)];
                *reinterpret_cast<uint2*>(qp)     = make_uint2(qwA0, qwA1);
                *reinterpret_cast<uint2*>(qp + 2) = make_uint2(qwB0, qwB1);
            }
        }

        // prefetch next chunk's inputs (latency hidden behind GEMM+epilogue)
        if (chunk + 1 < NCHUNK) {
            size_t t = (size_t)(chunk + 1) * TC + (lane & 31);
            const float* p = inp + (t * B_DIM + b) * 9;
            float a = p[wv], r = p[4 + wv];
            actv = a; rav = a * r;
        }

        // ---- GEMM + epilogue, one 16-row m-tile at a time (acc regs halved)
        #pragma unroll
        for (int mi = 0; mi < 2; ++mi) {
            const int mt = wv * 2 + mi;
            f32x4 acc[9];
            #pragma unroll
            for (int nt = 0; nt < 9; ++nt)              // beta folded into acc init
                acc[nt] = (f32x4){breg[nt], breg[nt], breg[nt], breg[nt]};

            #pragma unroll
            for (int kt = 0; kt < 4; ++kt) {
                bf16x8 afr = *(const bf16x8*)&Hb16[(size_t)(mt * 16 + ml) * LDH + kt * 32 + qd * 8];
                #pragma unroll
                for (int nt = 0; nt < 9; ++nt)
                    acc[nt] = __builtin_amdgcn_mfma_f32_16x16x32_bf16(afr, bfr[nt][kt], acc[nt], 0, 0, 0);
            }

            // kappa tile: col 128 lives at nt=8, ml==0; Q there == 1, beta == 0
            bool km = (ml == 0);
            float p0 = km ? acc[8][0] : 0.f;
            float p1 = km ? acc[8][1] : 0.f;
            float p2 = km ? acc[8][2] : 0.f;
            float p3 = km ? acc[8][3] : 0.f;

            const int m2e = mt * 8 + qd * 2;            // global row-pair of rows row0,row0+1
            // reader base: col 16nt+ml -> colpair 8nt+(ml>>1), parity ml&1
            const uint32_t* qr = &Qt[(ml >> 1) * 130 + (ml & 1) + 2 * m2e];
            #pragma unroll
            for (int nt = 0; nt < 8; ++nt) {
                uint32_t w0 = qr[nt * 1040];            // slot m2e   (rows row0,row0+1)
                uint32_t w1 = qr[nt * 1040 + 2];        // slot m2e+1 (rows row0+2,row0+3)
                p0 = fmaf(acc[nt][0], bfLO(w0), p0);
                p1 = fmaf(acc[nt][1], bfHI(w0), p1);
                p2 = fmaf(acc[nt][2], bfLO(w1), p2);
                p3 = fmaf(acc[nt][3], bfHI(w1), p3);
            }

            p0 = rowsum16(p0);
            p1 = rowsum16(p1);
            p2 = rowsum16(p2);
            p3 = rowsum16(p3);

            if (ml == 0) {
                int row0 = mt * 16 + qd * 4;
                #pragma unroll
                for (int r = 0; r < 4; ++r) {
                    int row = row0 + r;
                    int aa = row >> 5;
                    int tl = row & (TC - 1);
                    size_t t = (size_t)chunk * TC + tl;
                    float pv = (r == 0) ? p0 : (r == 1) ? p1 : (r == 2) ? p2 : p3;
                    out[(t * B_DIM + b) * A_DIM + aa] = pv;
                }
            }
        }
        // no barrier: next scan overwrites only this wave's own rows after its own reads
    }

    // ---- final q, h (fp32 state, exact recurrence)
    size_t qbase = (size_t)T_DIM * B_DIM * A_DIM;
    size_t off = (size_t)b * (A_DIM * D_DIM) + (size_t)wv * D_DIM + d0;
    *(float2*)&out[qbase + off] = make_float2(q0, q1);
    *(float2*)&out[qbase + (size_t)B_DIM * A_DIM * D_DIM + off] = make_float2(h0, h1);
}

extern "C" void kernel_launch(void* const* d_in, const int* in_sizes, int n_in,
                              void* d_out, int out_size, void* d_ws, size_t ws_size,
                              hipStream_t stream) {
    const float* inp    = (const float*)d_in[0];
    const float* phi_r  = (const float*)d_in[1];
    const float* chi_r  = (const float*)d_in[2];
    const float* beta_r = (const float*)d_in[3];
    const float* kap_r  = (const float*)d_in[4];
    const float* C_r    = (const float*)d_in[5];
    float* outp = (float*)d_out;
    gql_fused<<<dim3(B_DIM), dim3(256), 0, stream>>>(inp, phi_r, chi_r, beta_r, kap_r, C_r, outp);
}

// Round 9
// 572.317 us; speedup vs baseline: 4.1253x; 1.0511x over previous
//
#include <hip/hip_runtime.h>
#include <stdint.h>

#define T_DIM 2048
#define B_DIM 1024
#define A_DIM 4
#define D_DIM 128
#define TC 32
#define NCHUNK (T_DIM / TC)
#define LDH 136                 // Hb row stride in bf16 elems (68 dwords == 4 mod 32 -> conflict-free b128)
#define LDC 136                 // Ct staging row stride
#define HB_BYTES (128 * LDH * 2)        // 34816
// Qt pair-interleaved: dword(col,slot) = (col>>1)*130 + 2*slot + (col&1)
// Writer: 2x 8B stores/group, 4 lanes per bank-pair = conflict-free (R7: -23% SQ_LDS_BANK_CONFLICT)
#define SMEM_BYTES (HB_BYTES + 64 * 130 * 4)   // 34816 + 33280 = 68096 (<80KB -> 2 blocks/CU)

typedef __attribute__((ext_vector_type(8))) short bf16x8;
typedef __attribute__((ext_vector_type(4))) float f32x4;

__device__ __forceinline__ float clampf(float x, float lo, float hi) {
    return fminf(fmaxf(x, lo), hi);
}
__device__ __forceinline__ float sigclamp(float x) {
    return clampf(1.f / (1.f + __expf(-x)), 0.01f, 0.99f);
}
__device__ __forceinline__ uint16_t bf16rnd(float f) {
    uint32_t u = __builtin_bit_cast(uint32_t, f) + 0x8000u;   // round-nearest (ties away)
    return (uint16_t)(u >> 16);
}
// pack2(x,y) -> (bf16(y)<<16)|bf16(x) in 3 VALU ops
__device__ __forceinline__ uint32_t pack2(float x, float y) {
    uint32_t ux = __builtin_bit_cast(uint32_t, x) + 0x8000u;
    uint32_t uy = __builtin_bit_cast(uint32_t, y) + 0x8000u;
    return __builtin_amdgcn_perm(uy, ux, 0x07060302);
}
__device__ __forceinline__ float bfLO(uint32_t u) {
    return __builtin_bit_cast(float, u << 16);
}
__device__ __forceinline__ float bfHI(uint32_t u) {
    return __builtin_bit_cast(float, u & 0xFFFF0000u);
}
template <int CTRL>
__device__ __forceinline__ float dppadd(float x) {
    int xi = __builtin_bit_cast(int, x);
    int yi = __builtin_amdgcn_mov_dpp(xi, CTRL, 0xF, 0xF, false);
    return x + __builtin_bit_cast(float, yi);
}
// sum across the 16 lanes of each DPP row (our ml-groups) via row_ror 1,2,4,8
__device__ __forceinline__ float rowsum16(float x) {
    x = dppadd<0x121>(x);
    x = dppadd<0x122>(x);
    x = dppadd<0x124>(x);
    x = dppadd<0x128>(x);
    return x;
}

// One block per b; 4 waves; wave wv owns action a=wv. No main-loop barriers.
// Ct (B-fragments) in registers (144 regs, AGPR-backed), loaded once from an
// LDS staging area then overlaid by Hb/Qt. 2 blocks/CU (R6: launch_bounds(.,4)
// spills bfr -> 8.2GB scratch FETCH; keep 2).
//
// Scaled-variable scan (u = q/phi, v = h/chi):
//   u' = (1-phi) u + r*a        v' = (1-chi) v + a     (4 fma/step, NO muls)
// Gains folded at init into staged operands (NO LDS scratch this time --
// the r3/r4 sphi/schi arrays caused register spill, 30MB scratch WRITE):
//   C'[d][e] = chi_d*C[d][e]*phi_e   (chi_d via readlane(chi0/chi1, i);
//                                     phi_e one sigmoid: e == tid&127 const)
//   kappa'_k = kappa_k*chi_k         (wave 0 writes from its own chi regs)
//   beta'_n  = beta_n*phi_n          (own sigmoid; folded into acc init)
__global__ __launch_bounds__(256, 2)
void gql_fused(const float* __restrict__ inp,
               const float* __restrict__ phi_raw,
               const float* __restrict__ chi_raw,
               const float* __restrict__ beta_raw,
               const float* __restrict__ kappa_raw,
               const float* __restrict__ C_raw,
               float* __restrict__ out)
{
    __shared__ __attribute__((aligned(16))) char smem[SMEM_BYTES];

    const int b    = blockIdx.x;
    const int tid  = threadIdx.x;
    const int lane = tid & 63;
    const int wv   = tid >> 6;
    const int ml   = lane & 15;
    const int qd   = lane >> 4;

    const int pid = (int)inp[(size_t)b * 9 + 8];

    // ---- scan params: thread owns (a=wv, d0=2*lane, d0+1)
    const int d0 = lane * 2;
    float2 pr = *(const float2*)(phi_raw + (size_t)pid * D_DIM + d0);
    float2 cr = *(const float2*)(chi_raw + (size_t)pid * D_DIM + d0);
    float phi0 = sigclamp(pr.x);
    float phi1 = sigclamp(pr.y);
    float chi0 = sigclamp(cr.x);
    float chi1 = sigclamp(cr.y);
    float omphi0 = 1.f - phi0, omphi1 = 1.f - phi1;
    float omchi0 = 1.f - chi0, omchi1 = 1.f - chi1;

    // ---- beta' = clamp(softplus(beta),.1,10) * phi_n (own sigmoid; init-only)
    float breg[9];
    #pragma unroll
    for (int nt = 0; nt < 8; ++nt) {
        float x = beta_raw[(size_t)pid * D_DIM + nt * 16 + ml];
        float p = sigclamp(phi_raw[(size_t)pid * D_DIM + nt * 16 + ml]);
        breg[nt] = clampf(log1pf(__expf(x)), 0.1f, 10.0f) * p;
    }
    breg[8] = 0.f;

    // ---- stage Ct[n=e][k=d] = bf16(chi_d * clip(C[d][e]) * phi_e)
    {
        uint16_t* Ct = (uint16_t*)smem;
        const float* Cp = C_raw + (size_t)pid * (D_DIM * D_DIM);
        // e = (i*256+tid)&127 = tid&127 (thread-invariant); d = 2i + (tid>>7)
        const float sphiE = sigclamp(phi_raw[(size_t)pid * D_DIM + (tid & 127)]);
        const int c0i = __builtin_bit_cast(int, chi0);
        const int c1i = __builtin_bit_cast(int, chi1);
        const int chsel = (tid >> 7) ? c1i : c0i;   // wave-uniform pick (d parity)
        #pragma unroll 8
        for (int i = 0; i < 64; ++i) {
            int idx = i * 256 + tid;
            int d = idx >> 7, e = idx & 127;
            float chD = __builtin_bit_cast(float, __builtin_amdgcn_readlane(chsel, i));
            Ct[e * LDC + d] = bf16rnd(clampf(Cp[idx], -10.f, 10.f) * chD * sphiE);
        }
        // kappa tile: zero-fill all except (n==0, k<128)
        for (int i = tid; i < 16 * LDC; i += 256) {
            int n = i / LDC;
            int k = i - n * LDC;
            if (!(n == 0 && k < D_DIM))
                Ct[(128 + n) * LDC + k] = 0;
        }
        // kappa' = clamp(kappa)*chi from wave 0's own regs (k0 = 2*tid)
        if (tid < 64) {
            float k0 = clampf(kappa_raw[(size_t)pid * D_DIM + 2 * tid], -10.f, 10.f);
            float k1 = clampf(kappa_raw[(size_t)pid * D_DIM + 2 * tid + 1], -10.f, 10.f);
            Ct[128 * LDC + 2 * tid]     = bf16rnd(k0 * chi0);
            Ct[128 * LDC + 2 * tid + 1] = bf16rnd(k1 * chi1);
        }
    }
    __syncthreads();

    // ---- B-fragments to registers (chunk-invariant): bfr[nt][kt]
    bf16x8 bfr[9][4];
    {
        const uint16_t* Ct = (const uint16_t*)smem;
        #pragma unroll
        for (int nt = 0; nt < 9; ++nt)
            #pragma unroll
            for (int kt = 0; kt < 4; ++kt)
                bfr[nt][kt] = *(const bf16x8*)&Ct[(nt * 16 + ml) * LDC + kt * 32 + qd * 8];
    }
    __syncthreads();   // staging area now dead; reuse as Hb/Qt

    uint32_t* H32 = (uint32_t*)smem;                    // Hb[m][k] = bf16(v)-pairs, dword idx m*68+dpair
    uint32_t* Qt  = (uint32_t*)(smem + HB_BYTES);       // Qt pair-interleaved bf16(u) (see top)
    const uint16_t* Hb16 = (const uint16_t*)smem;

    // ---- per-chunk wave-uniform inputs via readlane: lane l<32 holds step l
    float actv, rav;
    {
        size_t t = (size_t)(lane & 31);
        const float* p = inp + (t * B_DIM + b) * 9;
        float a = p[wv], r = p[4 + wv];
        actv = a; rav = a * r;
    }

    const int qtw = lane * 130 + wv * 32;   // Qt writer base (dwords): + (tl-3) per group

    // scaled state: u = q/phi, v = h/chi  (q0 = 0.5, h0 = 0)
    float u0 = 0.5f / phi0, u1 = 0.5f / phi1, v0 = 0.f, v1 = 0.f;

    for (int chunk = 0; chunk < NCHUNK; ++chunk) {
        const int ai = __builtin_bit_cast(int, actv);
        const int ri = __builtin_bit_cast(int, rav);

        // ---- scan: 32 steps, 4 fma/step, register-only except paired LDS stores
        uint32_t hw_prev = 0, qwA0 = 0, qwA1 = 0;
        float u0p = 0.f, u1p = 0.f;
        #pragma unroll
        for (int tl = 0; tl < TC; ++tl) {
            float sa = __builtin_bit_cast(float, __builtin_amdgcn_readlane(ai, tl));
            float sr = __builtin_bit_cast(float, __builtin_amdgcn_readlane(ri, tl));
            u0 = fmaf(omphi0, u0, sr);
            u1 = fmaf(omphi1, u1, sr);
            v0 = fmaf(omchi0, v0, sa);
            v1 = fmaf(omchi1, v1, sa);
            uint32_t hw = pack2(v0, v1);
            if (tl & 1) {
                int m = wv * TC + tl - 1;
                H32[m * 68 + lane] = hw_prev;           // rows m, m+1: ds_write2-mergeable
                H32[(m + 1) * 68 + lane] = hw;
            } else {
                hw_prev = hw;
            }
            if ((tl & 1) == 0) {
                u0p = u0; u1p = u1;
            } else if ((tl & 3) == 1) {
                qwA0 = pack2(u0p, u0);                  // col d0, rows tl-1,tl
                qwA1 = pack2(u1p, u1);                  // col d0+1
            } else {                                    // tl&3 == 3
                uint32_t qwB0 = pack2(u0p, u0);
                uint32_t qwB1 = pack2(u1p, u1);
                uint32_t* qp = &Qt[qtw + (tl - 3)];
                *reinterpret_cast<uint2*>(qp)     = make_uint2(qwA0, qwA1);
                *reinterpret_cast<uint2*>(qp + 2) = make_uint2(qwB0, qwB1);
            }
        }

        // prefetch next chunk's inputs (latency hidden behind GEMM+epilogue)
        if (chunk + 1 < NCHUNK) {
            size_t t = (size_t)(chunk + 1) * TC + (lane & 31);
            const float* p = inp + (t * B_DIM + b) * 9;
            float a = p[wv], r = p[4 + wv];
            actv = a; rav = a * r;
        }

        // ---- GEMM + epilogue, one 16-row m-tile at a time (acc regs halved)
        #pragma unroll
        for (int mi = 0; mi < 2; ++mi) {
            const int mt = wv * 2 + mi;
            f32x4 acc[9];
            #pragma unroll
            for (int nt = 0; nt < 9; ++nt)              // beta' folded into acc init
                acc[nt] = (f32x4){breg[nt], breg[nt], breg[nt], breg[nt]};

            #pragma unroll
            for (int kt = 0; kt < 4; ++kt) {
                bf16x8 afr = *(const bf16x8*)&Hb16[(size_t)(mt * 16 + ml) * LDH + kt * 32 + qd * 8];
                #pragma unroll
                for (int nt = 0; nt < 9; ++nt)
                    acc[nt] = __builtin_amdgcn_mfma_f32_16x16x32_bf16(afr, bfr[nt][kt], acc[nt], 0, 0, 0);
            }

            // kappa tile: col 128 lives at nt=8, ml==0; Q there == 1, beta' == 0
            bool km = (ml == 0);
            float p0 = km ? acc[8][0] : 0.f;
            float p1 = km ? acc[8][1] : 0.f;
            float p2 = km ? acc[8][2] : 0.f;
            float p3 = km ? acc[8][3] : 0.f;

            const int m2e = mt * 8 + qd * 2;            // global row-pair of rows row0,row0+1
            // reader base: col 16nt+ml -> colpair 8nt+(ml>>1), parity ml&1
            const uint32_t* qr = &Qt[(ml >> 1) * 130 + (ml & 1) + 2 * m2e];
            #pragma unroll
            for (int nt = 0; nt < 8; ++nt) {
                uint32_t w0 = qr[nt * 1040];            // slot m2e   (rows row0,row0+1)
                uint32_t w1 = qr[nt * 1040 + 2];        // slot m2e+1 (rows row0+2,row0+3)
                p0 = fmaf(acc[nt][0], bfLO(w0), p0);
                p1 = fmaf(acc[nt][1], bfHI(w0), p1);
                p2 = fmaf(acc[nt][2], bfLO(w1), p2);
                p3 = fmaf(acc[nt][3], bfHI(w1), p3);
            }

            p0 = rowsum16(p0);
            p1 = rowsum16(p1);
            p2 = rowsum16(p2);
            p3 = rowsum16(p3);

            if (ml == 0) {
                int row0 = mt * 16 + qd * 4;
                #pragma unroll
                for (int r = 0; r < 4; ++r) {
                    int row = row0 + r;
                    int aa = row >> 5;
                    int tl = row & (TC - 1);
                    size_t t = (size_t)chunk * TC + tl;
                    float pv = (r == 0) ? p0 : (r == 1) ? p1 : (r == 2) ? p2 : p3;
                    out[(t * B_DIM + b) * A_DIM + aa] = pv;
                }
            }
        }
        // no barrier: next scan overwrites only this wave's own rows after its own reads
    }

    // ---- final q, h: rescale u,v back (phi = 1-omphi, recomputed to keep
    //      loop live-set minimal; <=1ulp from the original clamped sigmoid)
    float phr0 = 1.f - omphi0, phr1 = 1.f - omphi1;
    float chr0 = 1.f - omchi0, chr1 = 1.f - omchi1;
    size_t qbase = (size_t)T_DIM * B_DIM * A_DIM;
    size_t off = (size_t)b * (A_DIM * D_DIM) + (size_t)wv * D_DIM + d0;
    *(float2*)&out[qbase + off] = make_float2(phr0 * u0, phr1 * u1);
    *(float2*)&out[qbase + (size_t)B_DIM * A_DIM * D_DIM + off] = make_float2(chr0 * v0, chr1 * v1);
}

extern "C" void kernel_launch(void* const* d_in, const int* in_sizes, int n_in,
                              void* d_out, int out_size, void* d_ws, size_t ws_size,
                              hipStream_t stream) {
    const float* inp    = (const float*)d_in[0];
    const float* phi_r  = (const float*)d_in[1];
    const float* chi_r  = (const float*)d_in[2];
    const float* beta_r = (const float*)d_in[3];
    const float* kap_r  = (const float*)d_in[4];
    const float* C_r    = (const float*)d_in[5];
    float* outp = (float*)d_out;
    gql_fused<<<dim3(B_DIM), dim3(256), 0, stream>>>(inp, phi_r, chi_r, beta_r, kap_r, C_r, outp);
}